// Round 7
// baseline (88.233 us; speedup 1.0000x reference)
//
#include <hip/hip_runtime.h>
#include <hip/hip_fp16.h>

#define SPAN 20
#define REPEAT 90

// pred, gt: [4, 1, 512, 512] f32. h_offsets, w_offsets: [90] i32.
// out: scalar f32 = mean |l2norm(pred_rd) - l2norm(gt_rd)| over [B,Hb,Wb,R].

constexpr int W  = 512;
constexpr int Wb = 472;           // 512 - 2*SPAN
constexpr int TJ = 64;            // output tile width  (j)
constexpr int TI = 8;             // output tile height (i); 472/8 = 59 exact
constexpr int TW = TJ + 2 * SPAN; // 104 input tile width
constexpr int TH = TI + 2 * SPAN; // 48  input tile height
constexpr int QW = TW / 2;        // 52 pairs per row
constexpr int PLANE = TH * QW;    // 2496 8B elements per plane

union Q { __half2 h[2]; uint2 u; };

__global__ __launch_bounds__(256, 4) void rd_loss_kernel(
    const float* __restrict__ pred, const float* __restrict__ gt,
    const int* __restrict__ hoff, const int* __restrict__ woff,
    float* __restrict__ out)
{
    // Parity-duplicated pair planes: plane[pi] pair q = {x[2q+pi], x[2q+1+pi]}
    // with x = {p,g} packed as half2. Any (hoff,woff) shift becomes an ALIGNED
    // contiguous ds_read_b64 from plane[woff&1]. 2*2496*8 = 39936 B.
    __shared__ uint2 plane[2][PLANE];
    __shared__ float wsum[4];

    const int t  = threadIdx.x;
    const int bx = blockIdx.x;    // 0..7   j-tile
    const int by = blockIdx.y;    // 0..58  i-tile
    const int b  = blockIdx.z;    // 0..3   batch
    const int I0 = by * TI;
    const int J0 = bx * TJ;

    const float* pb_ = pred + b * (W * W);
    const float* gb_ = gt   + b * (W * W);

    // ---- stage both planes (rows always in range; cols clamped to 510,
    //      clamped junk only feeds masked-out pixels) ----
    for (int e = t; e < PLANE; e += 256) {
        const int row = e / QW;           // magic-mul div
        const int q   = e - row * QW;
        const int gr  = I0 + row;                       // <= 511 always
        int c0 = J0 + 2 * q;  c0 = c0 < 510 ? c0 : 510; // even -> float2 ok
        int c2 = c0 + 2;      c2 = c2 < 510 ? c2 : 510;
        const float2 pLo = *(const float2*)(pb_ + gr * W + c0);
        const float2 gLo = *(const float2*)(gb_ + gr * W + c0);
        const float2 pHi = *(const float2*)(pb_ + gr * W + c2);
        const float2 gHi = *(const float2*)(gb_ + gr * W + c2);
        const __half2 h0 = __floats2half2_rn(pLo.x, gLo.x);
        const __half2 h1 = __floats2half2_rn(pLo.y, gLo.y);
        const __half2 h2 = __floats2half2_rn(pHi.x, gHi.x);
        Q u0; u0.h[0] = h0; u0.h[1] = h1;   // {x[2q],   x[2q+1]}
        Q u1; u1.h[0] = h1; u1.h[1] = h2;   // {x[2q+1], x[2q+2]}
        plane[0][e] = u0.u;
        plane[1][e] = u1.u;
    }
    __syncthreads();

    // ---- 2 pixels per thread: (row, 2*jp) and (row, 2*jp+1) ----
    const int jp  = t & 31;               // pair 0..31
    const int row = t >> 5;               // 0..7
    const bool ok0 = (J0 + 2 * jp)     < Wb;
    const bool ok1 = (J0 + 2 * jp + 1) < Wb;

    const int lanebase = row * QW + jp;   // per-lane element index part
    Q cc; cc.u = plane[0][(SPAN + row) * QW + (SPAN / 2 + jp)];
    const __half2 c0 = cc.h[0], c1 = cc.h[1];

    // ---- pass 1: packed sum-of-squares, even/odd split accumulators ----
    __half2 sA0 = __floats2half2_rn(0.f, 0.f), sB0 = sA0;
    __half2 sA1 = sA0, sB1 = sA0;
    #pragma unroll
    for (int r = 0; r < REPEAT; ++r) {
        const int ho = hoff[r], wo = woff[r];          // uniform (s_load)
        const int pi = wo & 1;
        const int uo = (SPAN + ho) * QW + ((SPAN + wo - pi) >> 1);
        Q vv; vv.u = plane[pi][lanebase + uo];         // aligned b64
        const __half2 d0 = __hsub2(c0, vv.h[0]);
        const __half2 d1 = __hsub2(c1, vv.h[1]);
        if (r & 1) { sB0 = __hfma2(d0, d0, sB0); sB1 = __hfma2(d1, d1, sB1); }
        else       { sA0 = __hfma2(d0, d0, sA0); sA1 = __hfma2(d1, d1, sA1); }
    }
    const float ssp0 = __half2float(__low2half(sA0))  + __half2float(__low2half(sB0));
    const float ssg0 = __half2float(__high2half(sA0)) + __half2float(__high2half(sB0));
    const float ssp1 = __half2float(__low2half(sA1))  + __half2float(__low2half(sB1));
    const float ssg1 = __half2float(__high2half(sA1)) + __half2float(__high2half(sB1));

    const float invp0 = (ssp0 == 0.f) ? 1.f : rsqrtf(ssp0);
    const float invg0 = (ssg0 == 0.f) ? 1.f : rsqrtf(ssg0);
    const float invp1 = (ssp1 == 0.f) ? 1.f : rsqrtf(ssp1);
    const float invg1 = (ssg1 == 0.f) ? 1.f : rsqrtf(ssg1);

    // |dp*invp - dg*invg| = invp * |dp - (invg/invp)*dg|
    const __half nr0 = __float2half(-(invg0 / invp0));
    const __half nr1 = __float2half(-(invg1 / invp1));

    // ---- pass 2: re-read (cheap b64), 3 VALU per term ----
    __half a0A = __float2half(0.f), a0B = a0A, a1A = a0A, a1B = a0A;
    #pragma unroll
    for (int r = 0; r < REPEAT; ++r) {
        const int ho = hoff[r], wo = woff[r];
        const int pi = wo & 1;
        const int uo = (SPAN + ho) * QW + ((SPAN + wo - pi) >> 1);
        Q vv; vv.u = plane[pi][lanebase + uo];
        const __half2 d0 = __hsub2(c0, vv.h[0]);
        const __half2 d1 = __hsub2(c1, vv.h[1]);
        const __half s0 = __hfma(nr0, __high2half(d0), __low2half(d0));
        const __half s1 = __hfma(nr1, __high2half(d1), __low2half(d1));
        if (r & 1) { a0B = __hadd(a0B, __habs(s0)); a1B = __hadd(a1B, __habs(s1)); }
        else       { a0A = __hadd(a0A, __habs(s0)); a1A = __hadd(a1A, __habs(s1)); }
    }
    const float l0 = invp0 * (__half2float(a0A) + __half2float(a0B));
    const float l1 = invp1 * (__half2float(a1A) + __half2float(a1B));

    float lsum = (ok0 ? l0 : 0.f) + (ok1 ? l1 : 0.f);

    // ---- reduction: wave shuffle -> LDS -> one atomic per block ----
    #pragma unroll
    for (int o = 32; o > 0; o >>= 1) lsum += __shfl_down(lsum, o, 64);

    const int lane = t & 63;
    const int wid  = t >> 6;
    if (lane == 0) wsum[wid] = lsum;
    __syncthreads();

    if (t == 0) {
        const float s = wsum[0] + wsum[1] + wsum[2] + wsum[3];
        constexpr float scale = 1.0f / (4.0f * 472.0f * 472.0f * 90.0f);
        atomicAdd(out, s * scale);
    }
}

extern "C" void kernel_launch(void* const* d_in, const int* in_sizes, int n_in,
                              void* d_out, int out_size, void* d_ws, size_t ws_size,
                              hipStream_t stream) {
    const float* pred = (const float*)d_in[0];
    const float* gt   = (const float*)d_in[1];
    const int* hoff   = (const int*)d_in[2];
    const int* woff   = (const int*)d_in[3];
    float* out = (float*)d_out;

    // Harness poisons d_out once and never re-poisons between graph replays:
    // zero it on-stream every call (graph-capturable).
    hipMemsetAsync(out, 0, sizeof(float), stream);

    dim3 grid(8, 59, 4);   // (472/64, 472/8, B)
    rd_loss_kernel<<<grid, 256, 0, stream>>>(pred, gt, hoff, woff, out);
}